// Round 8
// baseline (358.430 us; speedup 1.0000x reference)
//
#include <hip/hip_runtime.h>
#include <hip/hip_bf16.h>
#include <hip/hip_cooperative_groups.h>

namespace cg = cooperative_groups;

typedef short s8v __attribute__((ext_vector_type(8)));
typedef float f4v __attribute__((ext_vector_type(4)));
typedef unsigned short u16;
typedef unsigned int u32;

// B=2, T=192, C=512, H=8, HS=64, ORDER=3; scale = 1/sqrt(64) = 0.125
#define SPLIT 4
#define ESC 0.18033688011112042f  // 0.125 * log2(e), folded into Q in phase 1

__device__ __forceinline__ u32 pack2bf(float lo, float hi) {
  u32 a = __builtin_bit_cast(u32, lo) + 0x8000u;
  u32 b = __builtin_bit_cast(u32, hi) + 0x8000u;
  return __builtin_amdgcn_perm(b, a, 0x07060302);  // {hi[31:16], lo[31:16]}
}
__device__ __forceinline__ u16 bf1(float f) {
  return (u16)((__builtin_bit_cast(u32, f) + 0x8000u) >> 16);
}
__device__ __forceinline__ f4v mfma16(s8v a, s8v b, f4v c) {
  return __builtin_amdgcn_mfma_f32_16x16x32_bf16(a, b, c, 0, 0, 0);
}

// ============ phase 1: projections. 480 items (slot, bh, 32-row tile) ======
__device__ __forceinline__ void phase1_proj(
    int item, int tid, char* smem,
    const float* __restrict__ x0, const float* __restrict__ x1,
    const float* __restrict__ x2,
    const float* __restrict__ qw, const float* __restrict__ qb,
    const float* __restrict__ kw, const float* __restrict__ kb,
    const float* __restrict__ vw, const float* __restrict__ vb,
    float* __restrict__ Q0f, float* __restrict__ K1f, float* __restrict__ V1f,
    u16* __restrict__ K2b, u16* __restrict__ V2b) {
  int wave = tid >> 6, lane = tid & 63, l15 = lane & 15, quad = lane >> 4;
  int slot = item / 96;
  int rem = item - slot * 96;
  int bh = rem / 6;
  int tt = rem - bh * 6;
  int b = bh >> 3, h = bh & 7;
  int t0 = tt * 32;

  const float* x; const float* w; const float* bias; int o;
  float* outf = nullptr; u16* outb = nullptr;
  switch (slot) {
    case 0: x = x0; w = qw; bias = qb; o = 0; outf = Q0f; break;
    case 1: x = x1; w = kw; bias = kb; o = 1; outf = K1f; break;
    case 2: x = x2; w = kw; bias = kb; o = 2; outb = K2b; break;
    case 3: x = x1; w = vw; bias = vb; o = 1; outf = V1f; break;
    default: x = x2; w = vw; bias = vb; o = 2; outb = V2b; break;
  }
  x += b * 192 * 512;
  w += (h * 3 + o) * 64 * 512;
  bias += (h * 3 + o) * 64;

  u16* xs = (u16*)smem;            // [32][68] bf16 (stride 17 dwords, odd)
  u16* wsx = (u16*)(smem + 4352);  // [64][68] bf16

  int mrow = (wave & 1) * 16 + l15;
  int nb = (wave >> 1) * 32;
  f4v acc0 = {0.f, 0.f, 0.f, 0.f}, acc1 = {0.f, 0.f, 0.f, 0.f};

  for (int kc = 0; kc < 8; ++kc) {
    int c0 = kc * 64;
    __syncthreads();  // protect xs/wsx WAR across kc and across items
#pragma unroll
    for (int r = 0; r < 2; ++r) {  // stage x chunk 32 x 64 -> bf16
      int idx = r * 256 + tid;
      int row = idx >> 4, c4 = idx & 15;
      float4 v = *(const float4*)(x + (t0 + row) * 512 + c0 + c4 * 4);
      uint2 st = {pack2bf(v.x, v.y), pack2bf(v.z, v.w)};
      *(uint2*)(xs + row * 68 + c4 * 4) = st;
    }
#pragma unroll
    for (int r = 0; r < 4; ++r) {  // stage w chunk 64 x 64 -> bf16
      int idx = r * 256 + tid;
      int row = idx >> 4, c4 = idx & 15;
      float4 v = *(const float4*)(w + row * 512 + c0 + c4 * 4);
      uint2 st = {pack2bf(v.x, v.y), pack2bf(v.z, v.w)};
      *(uint2*)(wsx + row * 68 + c4 * 4) = st;
    }
    __syncthreads();
#pragma unroll
    for (int kst = 0; kst < 2; ++kst) {
      s8v a = *(const s8v*)(xs + mrow * 68 + kst * 32 + quad * 8);
      s8v b0 = *(const s8v*)(wsx + (nb + l15) * 68 + kst * 32 + quad * 8);
      s8v b1 = *(const s8v*)(wsx + (nb + 16 + l15) * 68 + kst * 32 + quad * 8);
      acc0 = mfma16(a, b0, acc0);
      acc1 = mfma16(a, b1, acc1);
    }
  }
  __syncthreads();

  int mbase = (wave & 1) * 16 + quad * 4;
#pragma unroll
  for (int nt = 0; nt < 2; ++nt) {
    int col = nb + nt * 16 + l15;
    float bs = bias[col];
    f4v a = nt ? acc1 : acc0;
#pragma unroll
    for (int r = 0; r < 4; ++r) {
      int t = t0 + mbase + r;
      float v = a[r] + bs;
      if (slot == 0) v *= ESC;
      long base = ((long)(bh * 192 + t)) * 64 + col;
      if (outf) outf[base] = v;
      else outb[base] = bf1(v);
    }
  }
}

// ============ phase 2: attention. 768 items (sp, bh, 16-row i-tile) ========
__device__ __forceinline__ void phase2_attn(
    int item, int tid, char* smem,
    const float* __restrict__ Q0f, const float* __restrict__ K1f,
    const float* __restrict__ V1f, const u16* __restrict__ K2b,
    const u16* __restrict__ V2b, float* __restrict__ Op,
    float* __restrict__ lp) {
  int wave = tid >> 6, lane = tid & 63, l15 = lane & 15, quad = lane >> 4;
  int sp = item / 192;
  int rem = item - sp * 192;
  int bh = rem / 12;
  int itile = rem - bh * 12;
  int i0 = itile * 16;
  int js = sp * 48;

  __syncthreads();  // protect smem WAR across items / phases

  u16* V2Ts = (u16*)(smem + 24576);  // [64 d][200] u16, phys-interleaved k
  {
    const u32* src = (const u32*)K2b + bh * 6144;
#pragma unroll
    for (int r = 0; r < 24; ++r) {  // K2 as [192 k][64] u16 (stride 128 B)
      int idx = r * 256 + tid;
      int k = idx >> 5, d2 = idx & 31;
      *(u32*)(smem + k * 128 + d2 * 4) = src[idx];
    }
    const u32* vsrc = (const u32*)V2b + bh * 6144;
#pragma unroll
    for (int r = 0; r < 24; ++r) {  // V2^T with phys(k) interleave
      int idx = r * 256 + tid;
      int k = idx >> 5, d2 = idx & 31;
      u32 v = vsrc[idx];
      int wv = (k * 1366) >> 16;  // k/48
      int c = k - wv * 48;
      int phys = c < 32 ? wv * 32 + ((c & 15) << 1) + (c >> 4)
                        : 128 + wv * 16 + (c & 15);
      V2Ts[(d2 * 2) * 200 + phys] = (u16)v;
      V2Ts[(d2 * 2 + 1) * 200 + phys] = (u16)(v >> 16);
    }
  }
  __syncthreads();

  s8v k2f[3][2];  // S matmul: B[k=d][n=kcol] = K2[kcol][d]
#pragma unroll
  for (int nt = 0; nt < 3; ++nt)
#pragma unroll
    for (int ks = 0; ks < 2; ++ks) {
      int n = wave * 48 + nt * 16 + l15;
      k2f[nt][ks] = *(const s8v*)(smem + n * 128 + ks * 64 + quad * 16);
    }
  s8v v2f[6];  // PV matmul: B[kphys][n=d]
#pragma unroll
  for (int ks = 0; ks < 6; ++ks) {
    int d = wave * 16 + l15;
    v2f[ks] = *(const s8v*)((const char*)V2Ts + d * 400 + ks * 64 + quad * 16);
  }
  __syncthreads();

  // Q (pre-scaled by ESC) in the exact A-fragment slots:
  const float4* qp = (const float4*)(Q0f + (bh * 192 + i0 + l15) * 64);
  float4 q0 = qp[quad * 2], q1 = qp[quad * 2 + 1];
  float4 q2 = qp[8 + quad * 2], q3 = qp[9 + quad * 2];

  float Oacc[4] = {0.f, 0.f, 0.f, 0.f};
  float lacc[4] = {0.f, 0.f, 0.f, 0.f};
  const int dcol = wave * 16 + l15;

  int buf = 0;
  for (int j0 = js; j0 < js + 48; j0 += 4) {
    u16* PS = (u16*)(smem + buf * 26112);  // 4 x [16][204] u16 (408 B rows)

    float v1r[4];
#pragma unroll
    for (int jj = 0; jj < 4; ++jj)
      v1r[jj] = V1f[(bh * 192 + j0 + jj) * 64 + dcol];

    // ---- B phase: S = (Q*K1[j]) @ K2^T, P = exp2(S) -> PS[buf]
#pragma unroll
    for (int jj = 0; jj < 4; ++jj) {
      const float4* kp = (const float4*)(K1f + (bh * 192 + j0 + jj) * 64);
      float4 c0 = kp[quad * 2], c1 = kp[quad * 2 + 1];
      float4 c2 = kp[8 + quad * 2], c3 = kp[9 + quad * 2];
      union { s8v v; u32 w[4]; } A0, A1;
      A0.w[0] = pack2bf(q0.x * c0.x, q0.y * c0.y);
      A0.w[1] = pack2bf(q0.z * c0.z, q0.w * c0.w);
      A0.w[2] = pack2bf(q1.x * c1.x, q1.y * c1.y);
      A0.w[3] = pack2bf(q1.z * c1.z, q1.w * c1.w);
      A1.w[0] = pack2bf(q2.x * c2.x, q2.y * c2.y);
      A1.w[1] = pack2bf(q2.z * c2.z, q2.w * c2.w);
      A1.w[2] = pack2bf(q3.x * c3.x, q3.y * c3.y);
      A1.w[3] = pack2bf(q3.z * c3.z, q3.w * c3.w);

      f4v sc0 = {0.f, 0.f, 0.f, 0.f}, sc1 = sc0, sc2 = sc0;
      sc0 = mfma16(A0.v, k2f[0][0], sc0);
      sc0 = mfma16(A1.v, k2f[0][1], sc0);
      sc1 = mfma16(A0.v, k2f[1][0], sc1);
      sc1 = mfma16(A1.v, k2f[1][1], sc1);
      sc2 = mfma16(A0.v, k2f[2][0], sc2);
      sc2 = mfma16(A1.v, k2f[2][1], sc2);

      u16* psj = PS + jj * 3264;
#pragma unroll
      for (int r = 0; r < 4; ++r) {
        float p0 = __builtin_amdgcn_exp2f(sc0[r]);
        float p1 = __builtin_amdgcn_exp2f(sc1[r]);
        float p2 = __builtin_amdgcn_exp2f(sc2[r]);
        int row = quad * 4 + r;
        *(u32*)(psj + row * 204 + wave * 32 + l15 * 2) = pack2bf(p0, p1);
        psj[row * 204 + 128 + wave * 16 + l15] = bf1(p2);
        lacc[r] += p0 + p1 + p2;
      }
    }
    __syncthreads();  // the ONE barrier per batch

    // ---- C phase: W = P @ V2 (phys k-order matches v2f), O += V1*W
#pragma unroll
    for (int jj = 0; jj < 4; ++jj) {
      f4v w4 = {0.f, 0.f, 0.f, 0.f};
      const char* pb = (const char*)PS + jj * 6528 + l15 * 408;
#pragma unroll
      for (int ks = 0; ks < 6; ++ks)
        w4 = mfma16(*(const s8v*)(pb + ks * 64 + quad * 16), v2f[ks], w4);
#pragma unroll
      for (int r = 0; r < 4; ++r) Oacc[r] += v1r[jj] * w4[r];
    }
    buf ^= 1;
    // WAR safe: B(m+2) on this buf only runs after barrier(m+1), which all
    // waves reach only after finishing C(m).
  }
  __syncthreads();

  // ---- reduce l across lanes/waves, store partials
#pragma unroll
  for (int r = 0; r < 4; ++r)
#pragma unroll
    for (int off = 1; off < 16; off <<= 1)
      lacc[r] += __shfl_xor(lacc[r], off);
  float* lred = (float*)smem;
  if (l15 == 0) {
#pragma unroll
    for (int r = 0; r < 4; ++r) lred[wave * 16 + quad * 4 + r] = lacc[r];
  }
  __syncthreads();

  long obase = (long)(sp * 16 + bh) * 192 + i0;
#pragma unroll
  for (int r = 0; r < 4; ++r)
    Op[(obase + quad * 4 + r) * 64 + dcol] = Oacc[r];
  if (tid < 16)
    lp[(sp * 16 + bh) * 192 + i0 + tid] =
        lred[tid] + lred[16 + tid] + lred[32 + tid] + lred[48 + tid];
}

// ============ phase 3: output projection. 192 items (16m x 64n tiles) ======
__device__ __forceinline__ void phase3_outproj(
    int item, int tid, char* smem, const float* __restrict__ Op,
    const float* __restrict__ lp, const float* __restrict__ cw,
    const float* __restrict__ cb, float* __restrict__ out) {
  float* xs = (float*)smem;              // [32][20]  (2560 B)
  float* wsh = (float*)(smem + 2560);    // [32][68]  (8704 B)
  float* linv = (float*)(smem + 11264);  // [8][16]   (512 B)
  int mt = item >> 3, nt = item & 7;
  int m0 = mt * 16;
  int b = m0 / 192;
  int t0 = m0 - b * 192;
  int n0 = nt * 64;

  __syncthreads();  // protect smem WAR vs prior phase/item
  if (tid < 128) {
    int h = tid >> 4, ml = tid & 15;
    float s = 0.f;
#pragma unroll
    for (int sp = 0; sp < SPLIT; ++sp)
      s += lp[(sp * 16 + b * 8 + h) * 192 + t0 + ml];
    linv[h * 16 + ml] = 1.0f / s;
  }

  int mA = tid >> 3, clA = (tid & 7) * 4;  // A-stage (tid<128 only)
  int nB0 = tid >> 3, nB1 = (256 + tid) >> 3;
  int m = tid >> 4, nq = tid & 15;
  float acc[4] = {};

  float4 pA[SPLIT];
  float4 pW0, pW1;
  if (tid < 128) {
#pragma unroll
    for (int sp = 0; sp < SPLIT; ++sp)
      pA[sp] = *(const float4*)(
          Op + (long)((sp * 16 + b * 8) * 192 + t0 + mA) * 64 + clA);
  }
  pW0 = *(const float4*)(cw + (long)(n0 + nB0) * 512 + clA);
  pW1 = *(const float4*)(cw + (long)(n0 + nB1) * 512 + clA);
  __syncthreads();  // linv ready

  for (int kc = 0; kc < 16; ++kc) {
    int h = kc >> 1;
    if (tid < 128) {  // combine SPLIT partials, scale 1/l, store [c][m]
      float4 s = pA[0];
#pragma unroll
      for (int sp = 1; sp < SPLIT; ++sp) {
        s.x += pA[sp].x; s.y += pA[sp].y; s.z += pA[sp].z; s.w += pA[sp].w;
      }
      float li = linv[h * 16 + mA];
      xs[clA * 20 + mA] = s.x * li;
      xs[(clA + 1) * 20 + mA] = s.y * li;
      xs[(clA + 2) * 20 + mA] = s.z * li;
      xs[(clA + 3) * 20 + mA] = s.w * li;
    }
    wsh[clA * 68 + nB0] = pW0.x; wsh[(clA + 1) * 68 + nB0] = pW0.y;
    wsh[(clA + 2) * 68 + nB0] = pW0.z; wsh[(clA + 3) * 68 + nB0] = pW0.w;
    wsh[clA * 68 + nB1] = pW1.x; wsh[(clA + 1) * 68 + nB1] = pW1.y;
    wsh[(clA + 2) * 68 + nB1] = pW1.z; wsh[(clA + 3) * 68 + nB1] = pW1.w;
    __syncthreads();
    if (kc < 15) {  // prefetch next kc during compute
      int h2 = (kc + 1) >> 1, d2 = ((kc + 1) & 1) * 32;
      if (tid < 128) {
#pragma unroll
        for (int sp = 0; sp < SPLIT; ++sp)
          pA[sp] = *(const float4*)(
              Op + (long)((sp * 16 + b * 8 + h2) * 192 + t0 + mA) * 64 + d2 +
              clA);
      }
      pW0 = *(const float4*)(cw + (long)(n0 + nB0) * 512 + h2 * 64 + d2 + clA);
      pW1 = *(const float4*)(cw + (long)(n0 + nB1) * 512 + h2 * 64 + d2 + clA);
    }
#pragma unroll
    for (int c = 0; c < 32; ++c) {
      float a = xs[c * 20 + m];
      const float* bv = &wsh[c * 68 + nq * 4];
      acc[0] += a * bv[0]; acc[1] += a * bv[1];
      acc[2] += a * bv[2]; acc[3] += a * bv[3];
    }
    __syncthreads();
  }

  float4 bias = *(const float4*)(cb + n0 + nq * 4);
  float4 st;
  st.x = acc[0] + bias.x;
  st.y = acc[1] + bias.y;
  st.z = acc[2] + bias.z;
  st.w = acc[3] + bias.w;
  *(float4*)(out + (long)(b * 192 + t0 + m) * 512 + n0 + nq * 4) = st;
}

// ============ fused cooperative kernel (grid-size agnostic) ================
__global__ __launch_bounds__(256, 2) void fused_kernel(
    const float* x0, const float* x1, const float* x2,
    const float* qw, const float* qb, const float* kw, const float* kb,
    const float* vw, const float* vb, const float* cw, const float* cb,
    float* out, float* Q0f, float* K1f, float* V1f, u16* K2b, u16* V2b,
    float* Op, float* lp) {
  extern __shared__ char smem[];
  cg::grid_group grid = cg::this_grid();
  int nb = gridDim.x;
  int tid = threadIdx.x;

  for (int it = blockIdx.x; it < 480; it += nb)
    phase1_proj(it, tid, smem, x0, x1, x2, qw, qb, kw, kb, vw, vb,
                Q0f, K1f, V1f, K2b, V2b);
  grid.sync();
  for (int it = blockIdx.x; it < SPLIT * 192; it += nb)
    phase2_attn(it, tid, smem, Q0f, K1f, V1f, K2b, V2b, Op, lp);
  grid.sync();
  for (int it = blockIdx.x; it < 192; it += nb)
    phase3_outproj(it, tid, smem, Op, lp, cw, cb, out);
}

// ============ standalone fallback kernels ==================================
__global__ __launch_bounds__(256) void proj_kernel(
    const float* x0, const float* x1, const float* x2,
    const float* qw, const float* qb, const float* kw, const float* kb,
    const float* vw, const float* vb, float* Q0f, float* K1f, float* V1f,
    u16* K2b, u16* V2b) {
  extern __shared__ char smem[];
  phase1_proj(blockIdx.x, threadIdx.x, smem, x0, x1, x2, qw, qb, kw, kb,
              vw, vb, Q0f, K1f, V1f, K2b, V2b);
}
__global__ __launch_bounds__(256) void attn_kernel(
    const float* Q0f, const float* K1f, const float* V1f,
    const u16* K2b, const u16* V2b, float* Op, float* lp) {
  extern __shared__ char smem[];
  phase2_attn(blockIdx.x, threadIdx.x, smem, Q0f, K1f, V1f, K2b, V2b, Op, lp);
}
__global__ __launch_bounds__(256) void outproj_kernel(
    const float* Op, const float* lp, const float* cw, const float* cb,
    float* out) {
  extern __shared__ char smem[];
  phase3_outproj(blockIdx.x, threadIdx.x, smem, Op, lp, cw, cb, out);
}

extern "C" void kernel_launch(void* const* d_in, const int* in_sizes, int n_in,
                              void* d_out, int out_size, void* d_ws, size_t ws_size,
                              hipStream_t stream) {
  const float* x0 = (const float*)d_in[0];
  const float* x1 = (const float*)d_in[1];
  const float* x2 = (const float*)d_in[2];
  const float* qw = (const float*)d_in[3];
  const float* qb = (const float*)d_in[4];
  const float* kw = (const float*)d_in[5];
  const float* kb = (const float*)d_in[6];
  const float* vw = (const float*)d_in[7];
  const float* vb = (const float*)d_in[8];
  const float* cw = (const float*)d_in[9];
  const float* cb = (const float*)d_in[10];
  float* out = (float*)d_out;

  // workspace carve
  char* ws = (char*)d_ws;
  float* Q0f = (float*)(ws + 0);        // 16*192*64 f32 (pre-scaled by ESC)
  float* K1f = (float*)(ws + 786432);   // 16*192*64 f32
  float* V1f = (float*)(ws + 1572864);  // 16*192*64 f32
  u16* K2b = (u16*)(ws + 2359296);      // 16*192*64 bf16
  u16* V2b = (u16*)(ws + 2752512);      // 16*192*64 bf16
  float* Op = (float*)(ws + 3145728);   // SPLIT*16*192*64 f32
  float* lp = (float*)(ws + 3145728 + (size_t)SPLIT * 786432);

  void* args[] = {&x0, &x1, &x2, &qw, &qb, &kw, &kb, &vw, &vb, &cw, &cb,
                  &out, &Q0f, &K1f, &V1f, &K2b, &V2b, &Op, &lp};

  int maxb = 0;
  hipError_t qrc = hipOccupancyMaxActiveBlocksPerMultiprocessor(
      &maxb, fused_kernel, 256, (size_t)52224);
  int gridn = 512;  // conservative default: 2 blocks/CU * 256 CUs
  if (qrc == hipSuccess && maxb >= 1) {
    gridn = maxb * 256;
    if (gridn > 768) gridn = 768;
  }
  hipError_t rc = hipLaunchCooperativeKernel(
      (void*)fused_kernel, dim3(gridn), dim3(256), args, 52224, stream);
  if (rc != hipSuccess) {
    (void)hipGetLastError();  // clear sticky error, use 3-kernel fallback
    proj_kernel<<<480, 256, 13056, stream>>>(x0, x1, x2, qw, qb, kw, kb,
                                             vw, vb, Q0f, K1f, V1f, K2b, V2b);
    attn_kernel<<<SPLIT * 192, 256, 52224, stream>>>(Q0f, K1f, V1f, K2b, V2b,
                                                     Op, lp);
    outproj_kernel<<<192, 256, 11776, stream>>>(Op, lp, cw, cb, out);
  }
}

// Round 9
// 265.001 us; speedup vs baseline: 1.3526x; 1.3526x over previous
//
#include <hip/hip_runtime.h>
#include <hip/hip_bf16.h>

typedef short s8v __attribute__((ext_vector_type(8)));
typedef float f4v __attribute__((ext_vector_type(4)));
typedef unsigned short u16;
typedef unsigned int u32;

// B=2, T=192, C=512, H=8, HS=64, ORDER=3; scale = 1/sqrt(64) = 0.125
#define SPLIT 4
#define ESC 0.18033688011112042f  // 0.125 * log2(e), folded into Q in proj

__device__ __forceinline__ u32 pack2bf(float lo, float hi) {
  u32 a = __builtin_bit_cast(u32, lo) + 0x8000u;
  u32 b = __builtin_bit_cast(u32, hi) + 0x8000u;
  return __builtin_amdgcn_perm(b, a, 0x07060302);  // {hi[31:16], lo[31:16]}
}
__device__ __forceinline__ u16 bf1(float f) {
  return (u16)((__builtin_bit_cast(u32, f) + 0x8000u) >> 16);
}
__device__ __forceinline__ f4v mfma16(s8v a, s8v b, f4v c) {
  return __builtin_amdgcn_mfma_f32_16x16x32_bf16(a, b, c, 0, 0, 0);
}

// ============ projection kernel (MFMA). 480 blocks, LDS 13056 B ============
__global__ __launch_bounds__(256) void proj_kernel(
    const float* __restrict__ x0, const float* __restrict__ x1,
    const float* __restrict__ x2,
    const float* __restrict__ qw, const float* __restrict__ qb,
    const float* __restrict__ kw, const float* __restrict__ kb,
    const float* __restrict__ vw, const float* __restrict__ vb,
    float* __restrict__ Q0f, float* __restrict__ K1f, float* __restrict__ V1f,
    u16* __restrict__ K2b, u16* __restrict__ V2b) {
  extern __shared__ char smem[];
  int tid = threadIdx.x;
  int wave = tid >> 6, lane = tid & 63, l15 = lane & 15, quad = lane >> 4;
  int item = blockIdx.x;
  int slot = item / 96;
  int rem = item - slot * 96;
  int bh = rem / 6;
  int tt = rem - bh * 6;
  int b = bh >> 3, h = bh & 7;
  int t0 = tt * 32;

  const float* x; const float* w; const float* bias; int o;
  float* outf = nullptr; u16* outb = nullptr;
  switch (slot) {
    case 0: x = x0; w = qw; bias = qb; o = 0; outf = Q0f; break;
    case 1: x = x1; w = kw; bias = kb; o = 1; outf = K1f; break;
    case 2: x = x2; w = kw; bias = kb; o = 2; outb = K2b; break;
    case 3: x = x1; w = vw; bias = vb; o = 1; outf = V1f; break;
    default: x = x2; w = vw; bias = vb; o = 2; outb = V2b; break;
  }
  x += b * 192 * 512;
  w += (h * 3 + o) * 64 * 512;
  bias += (h * 3 + o) * 64;

  u16* xs = (u16*)smem;            // [32][68] bf16 (stride 17 dwords, odd)
  u16* wsx = (u16*)(smem + 4352);  // [64][68] bf16

  int mrow = (wave & 1) * 16 + l15;
  int nb = (wave >> 1) * 32;
  f4v acc0 = {0.f, 0.f, 0.f, 0.f}, acc1 = {0.f, 0.f, 0.f, 0.f};

  for (int kc = 0; kc < 8; ++kc) {
    int c0 = kc * 64;
    __syncthreads();  // protect xs/wsx WAR across kc
#pragma unroll
    for (int r = 0; r < 2; ++r) {  // stage x chunk 32 x 64 -> bf16
      int idx = r * 256 + tid;
      int row = idx >> 4, c4 = idx & 15;
      float4 v = *(const float4*)(x + (t0 + row) * 512 + c0 + c4 * 4);
      uint2 st = {pack2bf(v.x, v.y), pack2bf(v.z, v.w)};
      *(uint2*)(xs + row * 68 + c4 * 4) = st;
    }
#pragma unroll
    for (int r = 0; r < 4; ++r) {  // stage w chunk 64 x 64 -> bf16
      int idx = r * 256 + tid;
      int row = idx >> 4, c4 = idx & 15;
      float4 v = *(const float4*)(w + row * 512 + c0 + c4 * 4);
      uint2 st = {pack2bf(v.x, v.y), pack2bf(v.z, v.w)};
      *(uint2*)(wsx + row * 68 + c4 * 4) = st;
    }
    __syncthreads();
#pragma unroll
    for (int kst = 0; kst < 2; ++kst) {
      s8v a = *(const s8v*)(xs + mrow * 68 + kst * 32 + quad * 8);
      s8v b0 = *(const s8v*)(wsx + (nb + l15) * 68 + kst * 32 + quad * 8);
      s8v b1 = *(const s8v*)(wsx + (nb + 16 + l15) * 68 + kst * 32 + quad * 8);
      acc0 = mfma16(a, b0, acc0);
      acc1 = mfma16(a, b1, acc1);
    }
  }

  int mbase = (wave & 1) * 16 + quad * 4;
#pragma unroll
  for (int nt = 0; nt < 2; ++nt) {
    int col = nb + nt * 16 + l15;
    float bs = bias[col];
    f4v a = nt ? acc1 : acc0;
#pragma unroll
    for (int r = 0; r < 4; ++r) {
      int t = t0 + mbase + r;
      float v = a[r] + bs;
      if (slot == 0) v *= ESC;
      long base = ((long)(bh * 192 + t)) * 64 + col;
      if (outf) outf[base] = v;
      else outb[base] = bf1(v);
    }
  }
}

// ============ attention kernel (proven R5/R8 structure). 768 blocks ========
__global__ __launch_bounds__(256) void attn_kernel(
    const float* __restrict__ Q0f, const float* __restrict__ K1f,
    const float* __restrict__ V1f, const u16* __restrict__ K2b,
    const u16* __restrict__ V2b, float* __restrict__ Op,
    float* __restrict__ lp) {
  extern __shared__ char smem[];
  int tid = threadIdx.x;
  int wave = tid >> 6, lane = tid & 63, l15 = lane & 15, quad = lane >> 4;
  int item = blockIdx.x;
  int sp = item / 192;
  int rem = item - sp * 192;
  int bh = rem / 12;
  int itile = rem - bh * 12;
  int i0 = itile * 16;
  int js = sp * 48;

  u16* V2Ts = (u16*)(smem + 24576);  // [64 d][200] u16, phys-interleaved k
  {
    const u32* src = (const u32*)K2b + bh * 6144;
#pragma unroll
    for (int r = 0; r < 24; ++r) {  // K2 as [192 k][64] u16 (stride 128 B)
      int idx = r * 256 + tid;
      int k = idx >> 5, d2 = idx & 31;
      *(u32*)(smem + k * 128 + d2 * 4) = src[idx];
    }
    const u32* vsrc = (const u32*)V2b + bh * 6144;
#pragma unroll
    for (int r = 0; r < 24; ++r) {  // V2^T with phys(k) interleave
      int idx = r * 256 + tid;
      int k = idx >> 5, d2 = idx & 31;
      u32 v = vsrc[idx];
      int wv = (k * 1366) >> 16;  // k/48
      int c = k - wv * 48;
      int phys = c < 32 ? wv * 32 + ((c & 15) << 1) + (c >> 4)
                        : 128 + wv * 16 + (c & 15);
      V2Ts[(d2 * 2) * 200 + phys] = (u16)v;
      V2Ts[(d2 * 2 + 1) * 200 + phys] = (u16)(v >> 16);
    }
  }
  __syncthreads();

  s8v k2f[3][2];  // S matmul: B[k=d][n=kcol] = K2[kcol][d]
#pragma unroll
  for (int nt = 0; nt < 3; ++nt)
#pragma unroll
    for (int ks = 0; ks < 2; ++ks) {
      int n = wave * 48 + nt * 16 + l15;
      k2f[nt][ks] = *(const s8v*)(smem + n * 128 + ks * 64 + quad * 16);
    }
  s8v v2f[6];  // PV matmul: B[kphys][n=d]
#pragma unroll
  for (int ks = 0; ks < 6; ++ks) {
    int d = wave * 16 + l15;
    v2f[ks] = *(const s8v*)((const char*)V2Ts + d * 400 + ks * 64 + quad * 16);
  }
  __syncthreads();

  // Q (pre-scaled by ESC) in the exact A-fragment slots:
  const float4* qp = (const float4*)(Q0f + (bh * 192 + i0 + l15) * 64);
  float4 q0 = qp[quad * 2], q1 = qp[quad * 2 + 1];
  float4 q2 = qp[8 + quad * 2], q3 = qp[9 + quad * 2];

  float Oacc[4] = {0.f, 0.f, 0.f, 0.f};
  float lacc[4] = {0.f, 0.f, 0.f, 0.f};
  const int dcol = wave * 16 + l15;

  int buf = 0;
  for (int j0 = js; j0 < js + 48; j0 += 4) {
    u16* PS = (u16*)(smem + buf * 26112);  // 4 x [16][204] u16 (408 B rows)

    float v1r[4];
#pragma unroll
    for (int jj = 0; jj < 4; ++jj)
      v1r[jj] = V1f[(bh * 192 + j0 + jj) * 64 + dcol];

    // ---- B phase: S = (Q*K1[j]) @ K2^T, P = exp2(S) -> PS[buf]
#pragma unroll
    for (int jj = 0; jj < 4; ++jj) {
      const float4* kp = (const float4*)(K1f + (bh * 192 + j0 + jj) * 64);
      float4 c0 = kp[quad * 2], c1 = kp[quad * 2 + 1];
      float4 c2 = kp[8 + quad * 2], c3 = kp[9 + quad * 2];
      union { s8v v; u32 w[4]; } A0, A1;
      A0.w[0] = pack2bf(q0.x * c0.x, q0.y * c0.y);
      A0.w[1] = pack2bf(q0.z * c0.z, q0.w * c0.w);
      A0.w[2] = pack2bf(q1.x * c1.x, q1.y * c1.y);
      A0.w[3] = pack2bf(q1.z * c1.z, q1.w * c1.w);
      A1.w[0] = pack2bf(q2.x * c2.x, q2.y * c2.y);
      A1.w[1] = pack2bf(q2.z * c2.z, q2.w * c2.w);
      A1.w[2] = pack2bf(q3.x * c3.x, q3.y * c3.y);
      A1.w[3] = pack2bf(q3.z * c3.z, q3.w * c3.w);

      f4v sc0 = {0.f, 0.f, 0.f, 0.f}, sc1 = sc0, sc2 = sc0;
      sc0 = mfma16(A0.v, k2f[0][0], sc0);
      sc0 = mfma16(A1.v, k2f[0][1], sc0);
      sc1 = mfma16(A0.v, k2f[1][0], sc1);
      sc1 = mfma16(A1.v, k2f[1][1], sc1);
      sc2 = mfma16(A0.v, k2f[2][0], sc2);
      sc2 = mfma16(A1.v, k2f[2][1], sc2);

      u16* psj = PS + jj * 3264;
#pragma unroll
      for (int r = 0; r < 4; ++r) {
        float p0 = __builtin_amdgcn_exp2f(sc0[r]);
        float p1 = __builtin_amdgcn_exp2f(sc1[r]);
        float p2 = __builtin_amdgcn_exp2f(sc2[r]);
        int row = quad * 4 + r;
        *(u32*)(psj + row * 204 + wave * 32 + l15 * 2) = pack2bf(p0, p1);
        psj[row * 204 + 128 + wave * 16 + l15] = bf1(p2);
        lacc[r] += p0 + p1 + p2;
      }
    }
    __syncthreads();  // the ONE barrier per batch

    // ---- C phase: W = P @ V2 (phys k-order matches v2f), O += V1*W
#pragma unroll
    for (int jj = 0; jj < 4; ++jj) {
      f4v w4 = {0.f, 0.f, 0.f, 0.f};
      const char* pb = (const char*)PS + jj * 6528 + l15 * 408;
#pragma unroll
      for (int ks = 0; ks < 6; ++ks)
        w4 = mfma16(*(const s8v*)(pb + ks * 64 + quad * 16), v2f[ks], w4);
#pragma unroll
      for (int r = 0; r < 4; ++r) Oacc[r] += v1r[jj] * w4[r];
    }
    buf ^= 1;
    // WAR safe: B(m+2) on this buf only runs after barrier(m+1), which all
    // waves reach only after finishing C(m).
  }
  __syncthreads();

  // ---- reduce l across lanes/waves, store partials
#pragma unroll
  for (int r = 0; r < 4; ++r)
#pragma unroll
    for (int off = 1; off < 16; off <<= 1)
      lacc[r] += __shfl_xor(lacc[r], off);
  float* lred = (float*)smem;
  if (l15 == 0) {
#pragma unroll
    for (int r = 0; r < 4; ++r) lred[wave * 16 + quad * 4 + r] = lacc[r];
  }
  __syncthreads();

  long obase = (long)(sp * 16 + bh) * 192 + i0;
#pragma unroll
  for (int r = 0; r < 4; ++r)
    Op[(obase + quad * 4 + r) * 64 + dcol] = Oacc[r];
  if (tid < 16)
    lp[(sp * 16 + bh) * 192 + i0 + tid] =
        lred[tid] + lred[16 + tid] + lred[32 + tid] + lred[48 + tid];
}

// ============ output projection (MFMA, LDS-free, barrier-free) ============
// grid = 6 mt(64 rows) x 8 nt(64 cols) = 48 blocks; each of 4 waves owns an
// independent 16m x 64n tile. A-frags (split-combine + 1/l, bf16) and B-frags
// (cw rows, contiguous along K) load DIRECTLY from global in MFMA layout.
__global__ __launch_bounds__(256) void outproj_kernel(
    const float* __restrict__ Op, const float* __restrict__ lp,
    const float* __restrict__ cw, const float* __restrict__ cb,
    float* __restrict__ out) {
  int tid = threadIdx.x;
  int wave = tid >> 6, lane = tid & 63, l15 = lane & 15, quad = lane >> 4;
  int bx = blockIdx.x;
  int mt = bx >> 3, ntb = bx & 7;
  int m0 = mt * 64 + wave * 16;
  int b = m0 / 192;
  int t0 = m0 - b * 192;
  int n0 = ntb * 64;
  int tL = t0 + l15;  // this lane's A-row

  // 1/l per head for this lane's row
  float linv_h[8];
#pragma unroll
  for (int h = 0; h < 8; ++h) {
    float s = 0.f;
#pragma unroll
    for (int sp = 0; sp < SPLIT; ++sp)
      s += lp[(sp * 16 + b * 8 + h) * 192 + tL];
    linv_h[h] = 1.0f / s;
  }

  f4v acc[4] = {{0.f, 0.f, 0.f, 0.f},
                {0.f, 0.f, 0.f, 0.f},
                {0.f, 0.f, 0.f, 0.f},
                {0.f, 0.f, 0.f, 0.f}};

  for (int kc = 0; kc < 8; ++kc) {  // kc == head h; K-chunk = 64
#pragma unroll
    for (int kst = 0; kst < 2; ++kst) {
      int d0 = kst * 32 + quad * 8;
      // A-frag: combine SPLIT partials of Y[tL][h*64+d0..+8], scale, pack
      float4 s0 = {0.f, 0.f, 0.f, 0.f}, s1 = s0;
#pragma unroll
      for (int sp = 0; sp < SPLIT; ++sp) {
        const float* p =
            Op + (long)((sp * 16 + b * 8 + kc) * 192 + tL) * 64 + d0;
        float4 v0 = *(const float4*)p;
        float4 v1 = *(const float4*)(p + 4);
        s0.x += v0.x; s0.y += v0.y; s0.z += v0.z; s0.w += v0.w;
        s1.x += v1.x; s1.y += v1.y; s1.z += v1.z; s1.w += v1.w;
      }
      float li = linv_h[kc];
      union { s8v v; u32 w[4]; } A;
      A.w[0] = pack2bf(s0.x * li, s0.y * li);
      A.w[1] = pack2bf(s0.z * li, s0.w * li);
      A.w[2] = pack2bf(s1.x * li, s1.y * li);
      A.w[3] = pack2bf(s1.z * li, s1.w * li);

#pragma unroll
      for (int nt = 0; nt < 4; ++nt) {
        const float* wp = cw + (long)(n0 + nt * 16 + l15) * 512 + kc * 64 + d0;
        float4 b0 = *(const float4*)wp;
        float4 b1 = *(const float4*)(wp + 4);
        union { s8v v; u32 w[4]; } Bv;
        Bv.w[0] = pack2bf(b0.x, b0.y);
        Bv.w[1] = pack2bf(b0.z, b0.w);
        Bv.w[2] = pack2bf(b1.x, b1.y);
        Bv.w[3] = pack2bf(b1.z, b1.w);
        acc[nt] = mfma16(A.v, Bv.v, acc[nt]);
      }
    }
  }

  // D layout: row = quad*4 + r, col = l15
#pragma unroll
  for (int nt = 0; nt < 4; ++nt) {
    int n = n0 + nt * 16 + l15;
    float bs = cb[n];
#pragma unroll
    for (int r = 0; r < 4; ++r) {
      int t = t0 + quad * 4 + r;
      out[(long)(b * 192 + t) * 512 + n] = acc[nt][r] + bs;
    }
  }
}

extern "C" void kernel_launch(void* const* d_in, const int* in_sizes, int n_in,
                              void* d_out, int out_size, void* d_ws, size_t ws_size,
                              hipStream_t stream) {
  const float* x0 = (const float*)d_in[0];
  const float* x1 = (const float*)d_in[1];
  const float* x2 = (const float*)d_in[2];
  const float* qw = (const float*)d_in[3];
  const float* qb = (const float*)d_in[4];
  const float* kw = (const float*)d_in[5];
  const float* kb = (const float*)d_in[6];
  const float* vw = (const float*)d_in[7];
  const float* vb = (const float*)d_in[8];
  const float* cw = (const float*)d_in[9];
  const float* cb = (const float*)d_in[10];
  float* out = (float*)d_out;

  // workspace carve
  char* ws = (char*)d_ws;
  float* Q0f = (float*)(ws + 0);        // 16*192*64 f32 (pre-scaled by ESC)
  float* K1f = (float*)(ws + 786432);   // 16*192*64 f32
  float* V1f = (float*)(ws + 1572864);  // 16*192*64 f32
  u16* K2b = (u16*)(ws + 2359296);      // 16*192*64 bf16
  u16* V2b = (u16*)(ws + 2752512);      // 16*192*64 bf16
  float* Op = (float*)(ws + 3145728);   // SPLIT*16*192*64 f32
  float* lp = (float*)(ws + 3145728 + (size_t)SPLIT * 786432);

  proj_kernel<<<480, 256, 13056, stream>>>(x0, x1, x2, qw, qb, kw, kb, vw, vb,
                                           Q0f, K1f, V1f, K2b, V2b);
  attn_kernel<<<SPLIT * 192, 256, 52224, stream>>>(Q0f, K1f, V1f, K2b, V2b,
                                                   Op, lp);
  outproj_kernel<<<48, 256, 0, stream>>>(Op, lp, cw, cb, out);
}

// Round 10
// 186.944 us; speedup vs baseline: 1.9173x; 1.4175x over previous
//
#include <hip/hip_runtime.h>
#include <hip/hip_bf16.h>

typedef short s8v __attribute__((ext_vector_type(8)));
typedef float f4v __attribute__((ext_vector_type(4)));
typedef unsigned short u16;
typedef unsigned int u32;

// B=2, T=192, C=512, H=8, HS=64, ORDER=3; scale = 1/sqrt(64) = 0.125
#define SPLIT 4
#define ESC 0.18033688011112042f  // 0.125 * log2(e), folded into Q in proj

__device__ __forceinline__ u32 pack2bf(float lo, float hi) {
  u32 a = __builtin_bit_cast(u32, lo) + 0x8000u;
  u32 b = __builtin_bit_cast(u32, hi) + 0x8000u;
  return __builtin_amdgcn_perm(b, a, 0x07060302);  // {hi[31:16], lo[31:16]}
}
__device__ __forceinline__ u16 bf1(float f) {
  return (u16)((__builtin_bit_cast(u32, f) + 0x8000u) >> 16);
}
__device__ __forceinline__ f4v mfma16(s8v a, s8v b, f4v c) {
  return __builtin_amdgcn_mfma_f32_16x16x32_bf16(a, b, c, 0, 0, 0);
}

// ============ projection kernel (MFMA). 480 blocks, LDS 13056 B ============
__global__ __launch_bounds__(256) void proj_kernel(
    const float* __restrict__ x0, const float* __restrict__ x1,
    const float* __restrict__ x2,
    const float* __restrict__ qw, const float* __restrict__ qb,
    const float* __restrict__ kw, const float* __restrict__ kb,
    const float* __restrict__ vw, const float* __restrict__ vb,
    float* __restrict__ Q0f, float* __restrict__ K1f, float* __restrict__ V1f,
    u16* __restrict__ K2b, u16* __restrict__ V2b) {
  extern __shared__ char smem[];
  int tid = threadIdx.x;
  int wave = tid >> 6, lane = tid & 63, l15 = lane & 15, quad = lane >> 4;
  int item = blockIdx.x;
  int slot = item / 96;
  int rem = item - slot * 96;
  int bh = rem / 6;
  int tt = rem - bh * 6;
  int b = bh >> 3, h = bh & 7;
  int t0 = tt * 32;

  const float* x; const float* w; const float* bias; int o;
  float* outf = nullptr; u16* outb = nullptr;
  switch (slot) {
    case 0: x = x0; w = qw; bias = qb; o = 0; outf = Q0f; break;
    case 1: x = x1; w = kw; bias = kb; o = 1; outf = K1f; break;
    case 2: x = x2; w = kw; bias = kb; o = 2; outb = K2b; break;
    case 3: x = x1; w = vw; bias = vb; o = 1; outf = V1f; break;
    default: x = x2; w = vw; bias = vb; o = 2; outb = V2b; break;
  }
  x += b * 192 * 512;
  w += (h * 3 + o) * 64 * 512;
  bias += (h * 3 + o) * 64;

  u16* xs = (u16*)smem;            // [32][68] bf16 (stride 17 dwords, odd)
  u16* wsx = (u16*)(smem + 4352);  // [64][68] bf16

  int mrow = (wave & 1) * 16 + l15;
  int nb = (wave >> 1) * 32;
  f4v acc0 = {0.f, 0.f, 0.f, 0.f}, acc1 = {0.f, 0.f, 0.f, 0.f};

  for (int kc = 0; kc < 8; ++kc) {
    int c0 = kc * 64;
    __syncthreads();  // protect xs/wsx WAR across kc
#pragma unroll
    for (int r = 0; r < 2; ++r) {  // stage x chunk 32 x 64 -> bf16
      int idx = r * 256 + tid;
      int row = idx >> 4, c4 = idx & 15;
      float4 v = *(const float4*)(x + (t0 + row) * 512 + c0 + c4 * 4);
      uint2 st = {pack2bf(v.x, v.y), pack2bf(v.z, v.w)};
      *(uint2*)(xs + row * 68 + c4 * 4) = st;
    }
#pragma unroll
    for (int r = 0; r < 4; ++r) {  // stage w chunk 64 x 64 -> bf16
      int idx = r * 256 + tid;
      int row = idx >> 4, c4 = idx & 15;
      float4 v = *(const float4*)(w + row * 512 + c0 + c4 * 4);
      uint2 st = {pack2bf(v.x, v.y), pack2bf(v.z, v.w)};
      *(uint2*)(wsx + row * 68 + c4 * 4) = st;
    }
    __syncthreads();
#pragma unroll
    for (int kst = 0; kst < 2; ++kst) {
      s8v a = *(const s8v*)(xs + mrow * 68 + kst * 32 + quad * 8);
      s8v b0 = *(const s8v*)(wsx + (nb + l15) * 68 + kst * 32 + quad * 8);
      s8v b1 = *(const s8v*)(wsx + (nb + 16 + l15) * 68 + kst * 32 + quad * 8);
      acc0 = mfma16(a, b0, acc0);
      acc1 = mfma16(a, b1, acc1);
    }
  }

  int mbase = (wave & 1) * 16 + quad * 4;
#pragma unroll
  for (int nt = 0; nt < 2; ++nt) {
    int col = nb + nt * 16 + l15;
    float bs = bias[col];
    f4v a = nt ? acc1 : acc0;
#pragma unroll
    for (int r = 0; r < 4; ++r) {
      int t = t0 + mbase + r;
      float v = a[r] + bs;
      if (slot == 0) v *= ESC;
      long base = ((long)(bh * 192 + t)) * 64 + col;
      if (outf) outf[base] = v;
      else outb[base] = bf1(v);
    }
  }
}

// ============ attention kernel — BYTE-EXACT R5 (proven 67 us) =============
// grid = SPLIT*16*12 = 768 blocks, 256 threads (4 waves). LDS = 51200 B.
// P row stride 400 B: C-phase b128 reads have disjoint 4-bank spans with
// benign 2-way aliasing — DO NOT change to 408 (R9: 2x regression).
__global__ __launch_bounds__(256) void attn_kernel(
    const float* __restrict__ Q0f, const float* __restrict__ K1f,
    const float* __restrict__ V1f, const u16* __restrict__ K2b,
    const u16* __restrict__ V2b, float* __restrict__ Op,
    float* __restrict__ lp) {
  extern __shared__ char smem[];
  int bx = blockIdx.x;
  int sp = bx / 192;
  int rem = bx - sp * 192;
  int bh = rem / 12;
  int itile = rem - bh * 12;
  int i0 = itile * 16;
  int js = sp * 48;
  int tid = threadIdx.x;
  int wave = tid >> 6;
  int lane = tid & 63;
  int l15 = lane & 15;
  int quad = lane >> 4;

  u16* V2Ts = (u16*)(smem + 25600);  // [64 d][200] u16, phys-interleaved k
  {
    const u32* src = (const u32*)K2b + bh * 6144;
#pragma unroll
    for (int r = 0; r < 24; ++r) {  // K2 as [192 k][64] u16 (stride 128 B)
      int idx = r * 256 + tid;
      int k = idx >> 5, d2 = idx & 31;
      *(u32*)(smem + k * 128 + d2 * 4) = src[idx];
    }
    const u32* vsrc = (const u32*)V2b + bh * 6144;
#pragma unroll
    for (int r = 0; r < 24; ++r) {  // V2^T with phys(k) interleave
      int idx = r * 256 + tid;
      int k = idx >> 5, d2 = idx & 31;
      u32 v = vsrc[idx];
      int wv = (k * 1366) >> 16;  // k/48
      int c = k - wv * 48;
      int phys = c < 32 ? wv * 32 + ((c & 15) << 1) + (c >> 4)
                        : 128 + wv * 16 + (c & 15);
      V2Ts[(d2 * 2) * 200 + phys] = (u16)v;
      V2Ts[(d2 * 2 + 1) * 200 + phys] = (u16)(v >> 16);
    }
  }
  __syncthreads();

  s8v k2f[3][2];  // S matmul: B[k=d][n=kcol] = K2[kcol][d]
#pragma unroll
  for (int nt = 0; nt < 3; ++nt)
#pragma unroll
    for (int ks = 0; ks < 2; ++ks) {
      int n = wave * 48 + nt * 16 + l15;
      k2f[nt][ks] = *(const s8v*)(smem + n * 128 + ks * 64 + quad * 16);
    }
  s8v v2f[6];  // PV matmul: B[kphys][n=d]
#pragma unroll
  for (int ks = 0; ks < 6; ++ks) {
    int d = wave * 16 + l15;
    v2f[ks] = *(const s8v*)((const char*)V2Ts + d * 400 + ks * 64 + quad * 16);
  }
  __syncthreads();

  // Q (pre-scaled by ESC at proj) in the exact A-fragment slots:
  const float4* qp = (const float4*)(Q0f + (bh * 192 + i0 + l15) * 64);
  float4 q0 = qp[quad * 2], q1 = qp[quad * 2 + 1];
  float4 q2 = qp[8 + quad * 2], q3 = qp[9 + quad * 2];

  float Oacc[4] = {0.f, 0.f, 0.f, 0.f};
  float lacc[4] = {0.f, 0.f, 0.f, 0.f};
  const int dcol = wave * 16 + l15;

  int buf = 0;
  for (int j0 = js; j0 < js + 48; j0 += 4) {
    u16* PS = (u16*)(smem + buf * 25600);  // 4 x [16][200] u16

    float v1r[4];
#pragma unroll
    for (int jj = 0; jj < 4; ++jj)
      v1r[jj] = V1f[(bh * 192 + j0 + jj) * 64 + dcol];

    // ---- B phase: S = (Q*K1[j]) @ K2^T, P = exp2(S) -> PS[buf]
#pragma unroll
    for (int jj = 0; jj < 4; ++jj) {
      const float4* kp = (const float4*)(K1f + (bh * 192 + j0 + jj) * 64);
      float4 c0 = kp[quad * 2], c1 = kp[quad * 2 + 1];
      float4 c2 = kp[8 + quad * 2], c3 = kp[9 + quad * 2];
      union { s8v v; u32 w[4]; } A0, A1;
      A0.w[0] = pack2bf(q0.x * c0.x, q0.y * c0.y);
      A0.w[1] = pack2bf(q0.z * c0.z, q0.w * c0.w);
      A0.w[2] = pack2bf(q1.x * c1.x, q1.y * c1.y);
      A0.w[3] = pack2bf(q1.z * c1.z, q1.w * c1.w);
      A1.w[0] = pack2bf(q2.x * c2.x, q2.y * c2.y);
      A1.w[1] = pack2bf(q2.z * c2.z, q2.w * c2.w);
      A1.w[2] = pack2bf(q3.x * c3.x, q3.y * c3.y);
      A1.w[3] = pack2bf(q3.z * c3.z, q3.w * c3.w);

      f4v sc0 = {0.f, 0.f, 0.f, 0.f}, sc1 = sc0, sc2 = sc0;
      sc0 = mfma16(A0.v, k2f[0][0], sc0);
      sc0 = mfma16(A1.v, k2f[0][1], sc0);
      sc1 = mfma16(A0.v, k2f[1][0], sc1);
      sc1 = mfma16(A1.v, k2f[1][1], sc1);
      sc2 = mfma16(A0.v, k2f[2][0], sc2);
      sc2 = mfma16(A1.v, k2f[2][1], sc2);

      u16* psj = PS + jj * 3200;
#pragma unroll
      for (int r = 0; r < 4; ++r) {
        float p0 = __builtin_amdgcn_exp2f(sc0[r]);
        float p1 = __builtin_amdgcn_exp2f(sc1[r]);
        float p2 = __builtin_amdgcn_exp2f(sc2[r]);
        int row = quad * 4 + r;
        *(u32*)(psj + row * 200 + wave * 32 + l15 * 2) = pack2bf(p0, p1);
        psj[row * 200 + 128 + wave * 16 + l15] = bf1(p2);
        lacc[r] += p0 + p1 + p2;
      }
    }
    __syncthreads();  // the ONE barrier per batch

    // ---- C phase: W = P @ V2 (phys k-order matches v2f), O += V1*W
#pragma unroll
    for (int jj = 0; jj < 4; ++jj) {
      f4v w4 = {0.f, 0.f, 0.f, 0.f};
      const char* pb = (const char*)PS + jj * 6400 + l15 * 400;
#pragma unroll
      for (int ks = 0; ks < 6; ++ks)
        w4 = mfma16(*(const s8v*)(pb + ks * 64 + quad * 16), v2f[ks], w4);
#pragma unroll
      for (int r = 0; r < 4; ++r) Oacc[r] += v1r[jj] * w4[r];
    }
    buf ^= 1;
    // WAR safe: B(m+2) on this buf only runs after barrier(m+1), which all
    // waves reach only after finishing C(m).
  }
  __syncthreads();

  // ---- epilogue: reduce l across lanes/waves, store partials
#pragma unroll
  for (int r = 0; r < 4; ++r)
#pragma unroll
    for (int off = 1; off < 16; off <<= 1)
      lacc[r] += __shfl_xor(lacc[r], off);
  float* lred = (float*)smem;
  if (l15 == 0) {
#pragma unroll
    for (int r = 0; r < 4; ++r) lred[wave * 16 + quad * 4 + r] = lacc[r];
  }
  __syncthreads();

  long obase = (long)(sp * 16 + bh) * 192 + i0;
#pragma unroll
  for (int r = 0; r < 4; ++r)
    Op[(obase + quad * 4 + r) * 64 + dcol] = Oacc[r];
  if (tid < 16)
    lp[(sp * 16 + bh) * 192 + i0 + tid] =
        lred[tid] + lred[16 + tid] + lred[32 + tid] + lred[48 + tid];
}

// ============ output projection (MFMA, LDS-free, barrier-free) ============
// grid = 24 mt(16 rows) x 8 nt(64 cols) = 192 blocks; each of 4 waves owns a
// 16m x 16n tile (A-frags shared across waves via L2). A-frags combine SPLIT
// partials + 1/l and pack bf16; B-frags (cw rows, contiguous along K) load
// directly from global in MFMA layout. No LDS, no barriers.
__global__ __launch_bounds__(256) void outproj_kernel(
    const float* __restrict__ Op, const float* __restrict__ lp,
    const float* __restrict__ cw, const float* __restrict__ cb,
    float* __restrict__ out) {
  int tid = threadIdx.x;
  int wave = tid >> 6, lane = tid & 63, l15 = lane & 15, quad = lane >> 4;
  int bx = blockIdx.x;
  int mt = bx >> 3, ntb = bx & 7;
  int m0 = mt * 16;
  int b = m0 / 192;
  int t0 = m0 - b * 192;
  int n0 = ntb * 64 + wave * 16;
  int tL = t0 + l15;  // this lane's A-row

  // 1/l per head for this lane's row
  float linv_h[8];
#pragma unroll
  for (int h = 0; h < 8; ++h) {
    float s = 0.f;
#pragma unroll
    for (int sp = 0; sp < SPLIT; ++sp)
      s += lp[(sp * 16 + b * 8 + h) * 192 + tL];
    linv_h[h] = 1.0f / s;
  }

  f4v acc = {0.f, 0.f, 0.f, 0.f};

  for (int kc = 0; kc < 8; ++kc) {  // kc == head h; K-chunk = 64
#pragma unroll
    for (int kst = 0; kst < 2; ++kst) {
      int d0 = kst * 32 + quad * 8;
      // A-frag: combine SPLIT partials of Y[tL][h*64+d0..+8], scale, pack
      float4 s0 = {0.f, 0.f, 0.f, 0.f}, s1 = s0;
#pragma unroll
      for (int sp = 0; sp < SPLIT; ++sp) {
        const float* p =
            Op + (long)((sp * 16 + b * 8 + kc) * 192 + tL) * 64 + d0;
        float4 v0 = *(const float4*)p;
        float4 v1 = *(const float4*)(p + 4);
        s0.x += v0.x; s0.y += v0.y; s0.z += v0.z; s0.w += v0.w;
        s1.x += v1.x; s1.y += v1.y; s1.z += v1.z; s1.w += v1.w;
      }
      float li = linv_h[kc];
      union { s8v v; u32 w[4]; } A;
      A.w[0] = pack2bf(s0.x * li, s0.y * li);
      A.w[1] = pack2bf(s0.z * li, s0.w * li);
      A.w[2] = pack2bf(s1.x * li, s1.y * li);
      A.w[3] = pack2bf(s1.z * li, s1.w * li);

      const float* wp = cw + (long)(n0 + l15) * 512 + kc * 64 + d0;
      float4 b0 = *(const float4*)wp;
      float4 b1 = *(const float4*)(wp + 4);
      union { s8v v; u32 w[4]; } Bv;
      Bv.w[0] = pack2bf(b0.x, b0.y);
      Bv.w[1] = pack2bf(b0.z, b0.w);
      Bv.w[2] = pack2bf(b1.x, b1.y);
      Bv.w[3] = pack2bf(b1.z, b1.w);
      acc = mfma16(A.v, Bv.v, acc);
    }
  }

  // D layout: row = quad*4 + r, col = l15
  int n = n0 + l15;
  float bs = cb[n];
#pragma unroll
  for (int r = 0; r < 4; ++r) {
    int t = t0 + quad * 4 + r;
    out[(long)(b * 192 + t) * 512 + n] = acc[r] + bs;
  }
}

extern "C" void kernel_launch(void* const* d_in, const int* in_sizes, int n_in,
                              void* d_out, int out_size, void* d_ws, size_t ws_size,
                              hipStream_t stream) {
  const float* x0 = (const float*)d_in[0];
  const float* x1 = (const float*)d_in[1];
  const float* x2 = (const float*)d_in[2];
  const float* qw = (const float*)d_in[3];
  const float* qb = (const float*)d_in[4];
  const float* kw = (const float*)d_in[5];
  const float* kb = (const float*)d_in[6];
  const float* vw = (const float*)d_in[7];
  const float* vb = (const float*)d_in[8];
  const float* cw = (const float*)d_in[9];
  const float* cb = (const float*)d_in[10];
  float* out = (float*)d_out;

  // workspace carve
  char* ws = (char*)d_ws;
  float* Q0f = (float*)(ws + 0);        // 16*192*64 f32 (pre-scaled by ESC)
  float* K1f = (float*)(ws + 786432);   // 16*192*64 f32
  float* V1f = (float*)(ws + 1572864);  // 16*192*64 f32
  u16* K2b = (u16*)(ws + 2359296);      // 16*192*64 bf16
  u16* V2b = (u16*)(ws + 2752512);      // 16*192*64 bf16
  float* Op = (float*)(ws + 3145728);   // SPLIT*16*192*64 f32
  float* lp = (float*)(ws + 3145728 + (size_t)SPLIT * 786432);

  proj_kernel<<<480, 256, 13056, stream>>>(x0, x1, x2, qw, qb, kw, kb, vw, vb,
                                           Q0f, K1f, V1f, K2b, V2b);
  attn_kernel<<<SPLIT * 192, 256, 51200, stream>>>(Q0f, K1f, V1f, K2b, V2b,
                                                   Op, lp);
  outproj_kernel<<<192, 256, 0, stream>>>(Op, lp, cw, cb, out);
}